// Round 13
// baseline (68.628 us; speedup 1.0000x reference)
//
#include <hip/hip_runtime.h>

#define EPS 1e-5f

typedef _Float16 half8 __attribute__((ext_vector_type(8)));
typedef _Float16 half4 __attribute__((ext_vector_type(4)));
typedef float f32x16 __attribute__((ext_vector_type(16)));
typedef float f32x4v __attribute__((ext_vector_type(4)));

// Fragment layout for an [R x K] f16 matrix consumed as 32-row MFMA operand:
// element (row, k) -> ((row>>5)*(K/16) + (k>>4))*512 + ((k>>3)&1)*256 + (row&31)*8 + (k&7)
// wave fragment load for (rowgroup rg, kslice ks) = base + (rg*(K/16)+ks)*512 + lane*8
// = 64 lanes x 16 B contiguous (perfectly coalesced).

// ---------------------------------------------------------------------------
// pre_kernel: blocks 0..255 = hxhy via MFMA (w1 consumed directly, alpha/bias
// folded in epilogue; hy written in fragment layout); blocks 256..319 =
// weight prep (BN-fold w2/w3, cast w4; all written in fragment layout).
// ---------------------------------------------------------------------------
__global__ __launch_bounds__(256)
void pre_kernel(
    const float* __restrict__ x, const float* __restrict__ y,
    const float* __restrict__ w1, const float* __restrict__ b1,
    const float* __restrict__ g1, const float* __restrict__ be1,
    const float* __restrict__ m1, const float* __restrict__ v1,
    const float* __restrict__ w2, const float* __restrict__ b2,
    const float* __restrict__ g2, const float* __restrict__ be2,
    const float* __restrict__ m2, const float* __restrict__ v2,
    const float* __restrict__ w3, const float* __restrict__ b3,
    const float* __restrict__ g3, const float* __restrict__ be3,
    const float* __restrict__ m3, const float* __restrict__ v3,
    const float* __restrict__ w4,
    _Float16* __restrict__ hxh, _Float16* __restrict__ hyh,
    _Float16* __restrict__ w2h, _Float16* __restrict__ w3h,
    _Float16* __restrict__ w4h,
    float* __restrict__ b2f, float* __restrict__ b3f)
{
    const int t = threadIdx.x;

    if (blockIdx.x >= 256) {
        // ---------------- prep part (fragment-scattered writes) ----------------
        int tid = (blockIdx.x - 256) * 256 + t;
        const int nth = 64 * 256;
        for (int idx = tid; idx < 256 * 512; idx += nth) {
            int n = idx >> 9, k = idx & 511;
            float a = g2[n] * rsqrtf(v2[n] + EPS);
            int addr = ((n >> 5) * 32 + (k >> 4)) * 512 + ((k >> 3) & 1) * 256 + (n & 31) * 8 + (k & 7);
            w2h[addr] = (_Float16)(a * w2[idx]);
        }
        for (int idx = tid; idx < 128 * 256; idx += nth) {
            int n = idx >> 8, k = idx & 255;
            float a = g3[n] * rsqrtf(v3[n] + EPS);
            int addr = ((n >> 5) * 16 + (k >> 4)) * 512 + ((k >> 3) & 1) * 256 + (n & 31) * 8 + (k & 7);
            w3h[addr] = (_Float16)(a * w3[idx]);
        }
        for (int idx = tid; idx < 64 * 128; idx += nth) {
            int n = idx >> 7, k = idx & 127;
            int addr = ((n >> 5) * 8 + (k >> 4)) * 512 + ((k >> 3) & 1) * 256 + (n & 31) * 8 + (k & 7);
            w4h[addr] = (_Float16)w4[idx];
        }
        if (tid < 256) {
            float a = g2[tid] * rsqrtf(v2[tid] + EPS);
            b2f[tid] = a * b2[tid] + be2[tid] - m2[tid] * a;
        } else if (tid < 384) {
            int n = tid - 256;
            float a = g3[n] * rsqrtf(v3[n] + EPS);
            b3f[n] = a * b3[n] + be3[n] - m3[n] * a;
        }
        return;
    }

    // ---------------- hxhy part ----------------
    // bid: rg = 32-row group (32), ng = 128-col group (4), which = x/y (2)
    const int rg = blockIdx.x & 31;
    const int ng = (blockIdx.x >> 5) & 3;
    const int which = blockIdx.x >> 7;

    constexpr int LDA = 136;  // 272 B row stride
    __shared__ _Float16 sh[32 * 136 + 128 * 136] __attribute__((aligned(16)));
    _Float16* xa = sh;                 // [32][136]
    _Float16* wb = sh + 32 * 136;      // [128][136]

    const int rowbase = rg * 32;
    const float* src = which ? y : x;

    // stage A: 32 rows x 128 f32 -> f16
#pragma unroll
    for (int p = 0; p < 4; ++p) {
        int c = p * 256 + t;               // 0..1023 float4-chunks
        int r = c >> 5, fo = (c & 31) * 4;
        f32x4v v = *(const f32x4v*)(src + (size_t)(rowbase + r) * 128 + fo);
        half4 h; h[0] = (_Float16)v[0]; h[1] = (_Float16)v[1];
        h[2] = (_Float16)v[2]; h[3] = (_Float16)v[3];
        *(half4*)(xa + r * LDA + fo) = h;
    }
    // stage B: 128 n-rows x 128 k f32 -> f16 (w1 row-major, k-offset by which)
#pragma unroll
    for (int p = 0; p < 16; ++p) {
        int c = p * 256 + t;               // 0..4095
        int n = c >> 5, fo = (c & 31) * 4;
        f32x4v v = *(const f32x4v*)(w1 + (size_t)(ng * 128 + n) * 256 + which * 128 + fo);
        half4 h; h[0] = (_Float16)v[0]; h[1] = (_Float16)v[1];
        h[2] = (_Float16)v[2]; h[3] = (_Float16)v[3];
        *(half4*)(wb + n * LDA + fo) = h;
    }
    __syncthreads();

    const int wid = t >> 6;
    const int l = t & 63;
    const int l31 = l & 31, lh = l >> 5;

    f32x16 acc = (f32x16)0.f;
#pragma unroll
    for (int kc = 0; kc < 8; ++kc) {
        half8 af = *(const half8*)(xa + l31 * LDA + kc * 16 + lh * 8);
        half8 bf = *(const half8*)(wb + (wid * 32 + l31) * LDA + kc * 16 + lh * 8);
        acc = __builtin_amdgcn_mfma_f32_32x32x16_f16(af, bf, acc, 0, 0, 0);
    }

    const int n = ng * 128 + wid * 32 + l31;
    float alpha = g1[n] * rsqrtf(v1[n] + EPS);
    if (which == 0) {
        float bias = alpha * b1[n] + be1[n] - m1[n] * alpha;
#pragma unroll
        for (int r = 0; r < 16; ++r) {
            int m = (r & 3) + 8 * (r >> 2) + 4 * lh;
            hxh[(size_t)(rowbase + m) * 512 + n] = (_Float16)(alpha * acc[r] + bias);
        }
    } else {
        // hy in fragment layout (per-b region of 65536 halves; K16=32)
        const int ks = n >> 4, lhh = (n >> 3) & 1, c = n & 7;
#pragma unroll
        for (int r = 0; r < 16; ++r) {
            int m = (r & 3) + 8 * (r >> 2) + 4 * lh;
            int R = rowbase + m;                // global row = b*128 + j
            int bb = R >> 7, j = R & 127;
            int addr = bb * 65536 + ((j >> 5) * 32 + ks) * 512 + lhh * 256 + (j & 31) * 8 + c;
            hyh[addr] = (_Float16)(alpha * acc[r]);
        }
    }
}

// ---------------------------------------------------------------------------
// fused: one block per (b, i-pair). 1024 threads = 16 waves, 1 block/CU.
// SWAPPED OPERANDS everywhere (A=weights, B=activations): D comes out
// transposed, so each lane holds a fixed activation row j=l31 with
// 4-consecutive output channels per quad -> ALL epilogue LDS stores are
// half4/f32x4 vector writes (8x fewer LDS instructions than scalar b16).
// Activations stored row-major [j][chan] -> next layer's B-fragment reads
// keep the proven 0-conflict b128 pattern (LD stride == 4 mod 32 words).
// a1 = relu(hx+hy) staged once (zero redundancy), K-chunk 128, double-
// buffered (2 x 64 KB aliasing tail regions) -> 4 L2 barriers. Bias added
// in epilogue (float4 from L2-hot arrays). Tails: two concurrent 8-wave
// teams (one i each). LDS 143360 B.
// ---------------------------------------------------------------------------
__global__ __launch_bounds__(1024, 4)
void fused_kernel(
    const _Float16* __restrict__ hxh, const _Float16* __restrict__ hyh,
    const _Float16* __restrict__ w2h, const _Float16* __restrict__ w3h,
    const _Float16* __restrict__ w4h,
    const float* __restrict__ b2f, const float* __restrict__ b3f,
    const float* __restrict__ b4,
    float* __restrict__ out)
{
    constexpr int LD2 = 264;   // a2 row stride (halves): 528 B, 0-conflict b128
    constexpr int LD3 = 136;   // a3 row stride (halves): 272 B
    constexpr int LDE = 68;    // es row stride (f32): 272 B
    constexpr int REG = 67584; // per-team tail region bytes

    __shared__ char smem[8192 + 2 * REG] __attribute__((aligned(16)));
    _Float16* hxs = (_Float16*)smem;             // [2][512] f16  2048 B
    float* spart  = (float*)(smem + 2048);       // [2][8][64]    4096 B
    float* ss     = (float*)(smem + 6144);       // [2][64]        512 B
    char* R1 = smem + 8192;
    // L2 phase: a1 buffer [2 bufs][64 slices][512 halves] = 128 KB aliases R1.
    // slice (within buf) = iv*32 + rg*8 + ksl.
    _Float16* a1 = (_Float16*)R1;

    const int b  = blockIdx.x >> 6;              // 0..7
    const int ip = blockIdx.x & 63;              // 0..63
    const int i0 = ip * 2;
    const int t = threadIdx.x;
    const int wid = t >> 6;                      // 0..15
    const int l   = t & 63;
    const int l31 = l & 31;
    const int lh  = l >> 5;

    if (t < 128) {
        int iv = t >> 6;                         // 0,1
        *(half8*)(hxs + iv * 512 + (t & 63) * 8) =
            *(const half8*)(hxh + (size_t)(b * 128 + i0 + iv) * 512 + (t & 63) * 8);
    }
    __syncthreads();

    // ---------------- layer 2 (swapped): D[n][j] = w2 . a1^T ----------------
    const int u = wid >> 2, v = wid & 3;         // u: n-pair {2u,2u+1}, v: j-group
    const int sk2 = (v) * 2;                     // staging: rg=u, ksl in {sk2,sk2+1}
    const _Float16* hysrc = hyh + (size_t)b * 65536 + (size_t)u * 32 * 512 + l * 8;
    const _Float16* pa0 = w2h + (size_t)(2 * u) * 32 * 512 + l * 8;  // A = w2
    const _Float16* pa1 = pa0 + 32 * 512;

    f32x16 d0 = (f32x16)0.f, d1 = (f32x16)0.f;   // i0: n-groups 2u, 2u+1
    f32x16 e0 = (f32x16)0.f, e1 = (f32x16)0.f;   // i1

    half8 hyr0, hyr1;                            // staged hy fragments (named)

    auto SLOAD = [&](int c) {
        hyr0 = *(const half8*)(hysrc + (size_t)(c * 8 + sk2) * 512);
        hyr1 = *(const half8*)(hysrc + (size_t)(c * 8 + sk2 + 1) * 512);
    };
    auto SFIN = [&](int c) {
#pragma unroll
        for (int kk = 0; kk < 2; ++kk) {
            const int ksl = sk2 + kk;
            const int ksg = c * 8 + ksl;
            half8 hy = kk ? hyr1 : hyr0;
            half8 hx0 = *(const half8*)(hxs + ksg * 16 + lh * 8);
            half8 hx1 = *(const half8*)(hxs + 512 + ksg * 16 + lh * 8);
            half8 s0 = hy + hx0;
            half8 s1 = hy + hx1;
            half8 a0, a1f;
#pragma unroll
            for (int cc = 0; cc < 8; ++cc) {
                a0[cc]  = s0[cc] > (_Float16)0.f ? s0[cc] : (_Float16)0.f;
                a1f[cc] = s1[cc] > (_Float16)0.f ? s1[cc] : (_Float16)0.f;
            }
            _Float16* dst = a1 + (size_t)((c & 1) * 64 + u * 8 + ksl) * 512 + l * 8;
            *(half8*)dst = a0;
            *(half8*)(dst + 32 * 512) = a1f;     // i1 slices at +32
        }
    };
    auto CONSUME = [&](int c) {
#pragma unroll 4
        for (int ksl = 0; ksl < 8; ++ksl) {
            const _Float16* bsl = a1 + (size_t)((c & 1) * 64 + v * 8 + ksl) * 512 + l * 8;
            half8 Bi0 = *(const half8*)bsl;
            half8 Bi1 = *(const half8*)(bsl + 32 * 512);
            half8 A0 = *(const half8*)(pa0 + (size_t)(c * 8 + ksl) * 512);
            half8 A1 = *(const half8*)(pa1 + (size_t)(c * 8 + ksl) * 512);
            d0 = __builtin_amdgcn_mfma_f32_32x32x16_f16(A0, Bi0, d0, 0, 0, 0);
            d1 = __builtin_amdgcn_mfma_f32_32x32x16_f16(A1, Bi0, d1, 0, 0, 0);
            e0 = __builtin_amdgcn_mfma_f32_32x32x16_f16(A0, Bi1, e0, 0, 0, 0);
            e1 = __builtin_amdgcn_mfma_f32_32x32x16_f16(A1, Bi1, e1, 0, 0, 0);
        }
    };

    SLOAD(0);
    SFIN(0);
    __syncthreads();
    for (int c = 0; c < 4; ++c) {
        if (c < 3) SLOAD(c + 1);
        CONSUME(c);
        if (c < 3) SFIN(c + 1);
        __syncthreads();
    }

    // ---------------- L2 epilogue: vector half4 stores, both regions --------
    {
        _Float16* a2_0 = (_Float16*)R1;          // team0 = i0
        _Float16* a2_1 = (_Float16*)(R1 + REG);  // team1 = i1
        const int j2 = v * 32 + l31;
#pragma unroll
        for (int g = 0; g < 2; ++g) {
            const f32x16 cd = g ? d1 : d0;
            const f32x16 ce = g ? e1 : e0;
            const int ngb = (2 * u + g) * 32;
#pragma unroll
            for (int q = 0; q < 4; ++q) {
                const int no = ngb + 8 * q + 4 * lh;
                f32x4v bv = *(const f32x4v*)(b2f + no);
                half4 h0, h1;
#pragma unroll
                for (int cc = 0; cc < 4; ++cc) {
                    h0[cc] = (_Float16)fmaxf(cd[4 * q + cc] + bv[cc], 0.f);
                    h1[cc] = (_Float16)fmaxf(ce[4 * q + cc] + bv[cc], 0.f);
                }
                *(half4*)(a2_0 + j2 * LD2 + no) = h0;
                *(half4*)(a2_1 + j2 * LD2 + no) = h1;
            }
        }
    }
    __syncthreads();

    // ---------------- concurrent team tails (team = wid>>3, one i each) -----
    const int team = wid >> 3;
    const int tw   = wid & 7;                    // team-local wave id
    char* reg = R1 + team * REG;
    _Float16* a2 = (_Float16*)reg;               // [128][264]  (j, n)
    _Float16* a3 = (_Float16*)reg;               // [128][136]  (j, o) after L3
    float*    es = (float*)reg;                  // [128][68]   (j, p) after L4
    float* spart_t = spart + team * 512;
    float* ss_t    = ss + team * 64;
    const int iv = i0 + team;

    // layer 3 (swapped): D[o][j] = w3 . a2^T ; wave: uo = o-pair, vj = j-group
    const int uo = tw >> 2, vj = tw & 3;
    const int j3 = vj * 32 + l31;
    f32x16 g0 = (f32x16)0.f, g1 = (f32x16)0.f;
#pragma unroll 4
    for (int kc = 0; kc < 16; ++kc) {
        half8 A0 = *(const half8*)(w3h + ((2 * uo) * 16 + kc) * 512 + l * 8);
        half8 A1 = *(const half8*)(w3h + ((2 * uo + 1) * 16 + kc) * 512 + l * 8);
        half8 Bf = *(const half8*)(a2 + j3 * LD2 + kc * 16 + lh * 8);
        g0 = __builtin_amdgcn_mfma_f32_32x32x16_f16(A0, Bf, g0, 0, 0, 0);
        g1 = __builtin_amdgcn_mfma_f32_32x32x16_f16(A1, Bf, g1, 0, 0, 0);
    }
    __syncthreads();
    {
#pragma unroll
        for (int g = 0; g < 2; ++g) {
            const f32x16 cg = g ? g1 : g0;
            const int ogb = (2 * uo + g) * 32;
#pragma unroll
            for (int q = 0; q < 4; ++q) {
                const int oo = ogb + 8 * q + 4 * lh;
                f32x4v bv = *(const f32x4v*)(b3f + oo);
                half4 h;
#pragma unroll
                for (int cc = 0; cc < 4; ++cc)
                    h[cc] = (_Float16)fmaxf(cg[4 * q + cc] + bv[cc], 0.f);
                *(half4*)(a3 + j3 * LD3 + oo) = h;
            }
        }
    }
    __syncthreads();

    // layer 4 (swapped): D[p][j] = w4 . a3^T ; up = p-group (2), vj = j-group
    const int up = tw >> 2;                      // reuse 0,1 split
    f32x16 a4 = (f32x16)0.f;
#pragma unroll
    for (int kc = 0; kc < 8; ++kc) {
        half8 A = *(const half8*)(w4h + (up * 8 + kc) * 512 + l * 8);
        half8 B = *(const half8*)(a3 + j3 * LD3 + kc * 16 + lh * 8);
        a4 = __builtin_amdgcn_mfma_f32_32x32x16_f16(A, B, a4, 0, 0, 0);
    }
    __syncthreads();  // a3 reads done before es overwrites it
    {
#pragma unroll
        for (int q = 0; q < 4; ++q) {
            const int pp = up * 32 + 8 * q + 4 * lh;
            f32x4v bv = *(const f32x4v*)(b4 + pp);
            f32x4v vv;
#pragma unroll
            for (int cc = 0; cc < 4; ++cc) vv[cc] = a4[4 * q + cc] + bv[cc];
            *(f32x4v*)(es + j3 * LDE + pp) = vv;
        }
    }
    __syncthreads();

    // s = sum_j e[j][p] ; out[j] = sum_p e[j][p]*s[p]   (per team)
    {
        float sv = 0.f;
#pragma unroll
        for (int jj = 0; jj < 16; ++jj) sv += es[(tw + jj * 8) * LDE + l];
        spart_t[tw * 64 + l] = sv;
    }
    __syncthreads();
    if ((t & 511) < 64) {
        int tt = t & 63;
        float s2 = 0.f;
#pragma unroll
        for (int r = 0; r < 8; ++r) s2 += spart_t[r * 64 + tt];
        ss_t[tt] = s2;
    }
    __syncthreads();
    {
        const int tt = t & 511;
        const int j = tt >> 2, q = tt & 3;
        float p = 0.f;
#pragma unroll
        for (int c = 0; c < 16; ++c) {
            int k = q + 4 * c;               // k-interleaved: 2 lanes/bank
            p += es[j * LDE + k] * ss_t[k];
        }
        p += __shfl_xor(p, 1);
        p += __shfl_xor(p, 2);
        if (q == 0) out[(size_t)(b * 128 + iv) * 128 + j] = p;
    }
}

// ---------------------------------------------------------------------------
extern "C" void kernel_launch(void* const* d_in, const int* in_sizes, int n_in,
                              void* d_out, int out_size, void* d_ws, size_t ws_size,
                              hipStream_t stream)
{
    (void)in_sizes; (void)n_in; (void)out_size; (void)ws_size;

    const float* x   = (const float*)d_in[0];
    const float* y   = (const float*)d_in[1];
    const float* w1  = (const float*)d_in[2];
    const float* b1  = (const float*)d_in[3];
    const float* g1  = (const float*)d_in[4];
    const float* be1 = (const float*)d_in[5];
    const float* m1  = (const float*)d_in[6];
    const float* v1  = (const float*)d_in[7];
    const float* w2  = (const float*)d_in[8];
    const float* b2  = (const float*)d_in[9];
    const float* g2  = (const float*)d_in[10];
    const float* be2 = (const float*)d_in[11];
    const float* m2  = (const float*)d_in[12];
    const float* v2  = (const float*)d_in[13];
    const float* w3  = (const float*)d_in[14];
    const float* b3  = (const float*)d_in[15];
    const float* g3  = (const float*)d_in[16];
    const float* be3 = (const float*)d_in[17];
    const float* m3  = (const float*)d_in[18];
    const float* v3  = (const float*)d_in[19];
    const float* w4  = (const float*)d_in[20];
    const float* b4  = (const float*)d_in[21];
    float* out = (float*)d_out;

    // workspace layout (~2.44 MB)
    float* b2f = (float*)d_ws;                 // 256 f32
    float* b3f = b2f + 256;                    // 128 f32
    _Float16* w2h = (_Float16*)(b3f + 128);    // 131072 f16 (fragment layout)
    _Float16* w3h = w2h + 131072;              // 32768 f16  (fragment layout)
    _Float16* w4h = w3h + 32768;               // 8192 f16   (fragment layout)
    _Float16* hxh = w4h + 8192;                // 524288 f16 (linear)
    _Float16* hyh = hxh + 524288;              // 524288 f16 (fragment layout per b)

    hipLaunchKernelGGL(pre_kernel, dim3(320), dim3(256), 0, stream,
                       x, y, w1, b1, g1, be1, m1, v1,
                       w2, b2, g2, be2, m2, v2,
                       w3, b3, g3, be3, m3, v3,
                       w4,
                       hxh, hyh, w2h, w3h, w4h, b2f, b3f);

    hipLaunchKernelGGL(fused_kernel, dim3(512), dim3(1024), 0, stream,
                       hxh, hyh, w2h, w3h, w4h, b2f, b3f, b4, out);
}

// Round 16
// 62.374 us; speedup vs baseline: 1.1003x; 1.1003x over previous
//
#include <hip/hip_runtime.h>

#define EPS 1e-5f

typedef _Float16 half8 __attribute__((ext_vector_type(8)));
typedef _Float16 half4 __attribute__((ext_vector_type(4)));
typedef float f32x16 __attribute__((ext_vector_type(16)));
typedef float f32x4v __attribute__((ext_vector_type(4)));

// Fragment layout for an [R x K] f16 matrix consumed as 32-row MFMA operand:
// element (row, k) -> ((row>>5)*(K/16) + (k>>4))*512 + ((k>>3)&1)*256 + (row&31)*8 + (k&7)
// wave fragment load for (rowgroup rg, kslice ks) = base + (rg*(K/16)+ks)*512 + lane*8
// = 64 lanes x 16 B contiguous (perfectly coalesced).

// ---------------------------------------------------------------------------
// pre_kernel: blocks 0..255 = hxhy via MFMA (w1 consumed directly, alpha/bias
// folded in epilogue; hy written in fragment layout); blocks 256..319 =
// weight prep (BN-fold w2/w3, cast w4; all written in fragment layout).
// ---------------------------------------------------------------------------
__global__ __launch_bounds__(256)
void pre_kernel(
    const float* __restrict__ x, const float* __restrict__ y,
    const float* __restrict__ w1, const float* __restrict__ b1,
    const float* __restrict__ g1, const float* __restrict__ be1,
    const float* __restrict__ m1, const float* __restrict__ v1,
    const float* __restrict__ w2, const float* __restrict__ b2,
    const float* __restrict__ g2, const float* __restrict__ be2,
    const float* __restrict__ m2, const float* __restrict__ v2,
    const float* __restrict__ w3, const float* __restrict__ b3,
    const float* __restrict__ g3, const float* __restrict__ be3,
    const float* __restrict__ m3, const float* __restrict__ v3,
    const float* __restrict__ w4,
    _Float16* __restrict__ hxh, _Float16* __restrict__ hyh,
    _Float16* __restrict__ w2h, _Float16* __restrict__ w3h,
    _Float16* __restrict__ w4h,
    float* __restrict__ b2f, float* __restrict__ b3f)
{
    const int t = threadIdx.x;

    if (blockIdx.x >= 256) {
        // ---------------- prep part (fragment-scattered writes) ----------------
        int tid = (blockIdx.x - 256) * 256 + t;
        const int nth = 64 * 256;
        for (int idx = tid; idx < 256 * 512; idx += nth) {
            int n = idx >> 9, k = idx & 511;
            float a = g2[n] * rsqrtf(v2[n] + EPS);
            int addr = ((n >> 5) * 32 + (k >> 4)) * 512 + ((k >> 3) & 1) * 256 + (n & 31) * 8 + (k & 7);
            w2h[addr] = (_Float16)(a * w2[idx]);
        }
        for (int idx = tid; idx < 128 * 256; idx += nth) {
            int n = idx >> 8, k = idx & 255;
            float a = g3[n] * rsqrtf(v3[n] + EPS);
            int addr = ((n >> 5) * 16 + (k >> 4)) * 512 + ((k >> 3) & 1) * 256 + (n & 31) * 8 + (k & 7);
            w3h[addr] = (_Float16)(a * w3[idx]);
        }
        for (int idx = tid; idx < 64 * 128; idx += nth) {
            int n = idx >> 7, k = idx & 127;
            int addr = ((n >> 5) * 8 + (k >> 4)) * 512 + ((k >> 3) & 1) * 256 + (n & 31) * 8 + (k & 7);
            w4h[addr] = (_Float16)w4[idx];
        }
        if (tid < 256) {
            float a = g2[tid] * rsqrtf(v2[tid] + EPS);
            b2f[tid] = a * b2[tid] + be2[tid] - m2[tid] * a;
        } else if (tid < 384) {
            int n = tid - 256;
            float a = g3[n] * rsqrtf(v3[n] + EPS);
            b3f[n] = a * b3[n] + be3[n] - m3[n] * a;
        }
        return;
    }

    // ---------------- hxhy part ----------------
    // bid: rg = 32-row group (32), ng = 128-col group (4), which = x/y (2)
    const int rg = blockIdx.x & 31;
    const int ng = (blockIdx.x >> 5) & 3;
    const int which = blockIdx.x >> 7;

    constexpr int LDA = 136;  // 272 B row stride
    __shared__ _Float16 sh[32 * 136 + 128 * 136] __attribute__((aligned(16)));
    _Float16* xa = sh;                 // [32][136]
    _Float16* wb = sh + 32 * 136;      // [128][136]

    const int rowbase = rg * 32;
    const float* src = which ? y : x;

    // stage A: 32 rows x 128 f32 -> f16
#pragma unroll
    for (int p = 0; p < 4; ++p) {
        int c = p * 256 + t;               // 0..1023 float4-chunks
        int r = c >> 5, fo = (c & 31) * 4;
        f32x4v v = *(const f32x4v*)(src + (size_t)(rowbase + r) * 128 + fo);
        half4 h; h[0] = (_Float16)v[0]; h[1] = (_Float16)v[1];
        h[2] = (_Float16)v[2]; h[3] = (_Float16)v[3];
        *(half4*)(xa + r * LDA + fo) = h;
    }
    // stage B: 128 n-rows x 128 k f32 -> f16 (w1 row-major, k-offset by which)
#pragma unroll
    for (int p = 0; p < 16; ++p) {
        int c = p * 256 + t;               // 0..4095
        int n = c >> 5, fo = (c & 31) * 4;
        f32x4v v = *(const f32x4v*)(w1 + (size_t)(ng * 128 + n) * 256 + which * 128 + fo);
        half4 h; h[0] = (_Float16)v[0]; h[1] = (_Float16)v[1];
        h[2] = (_Float16)v[2]; h[3] = (_Float16)v[3];
        *(half4*)(wb + n * LDA + fo) = h;
    }
    __syncthreads();

    const int wid = t >> 6;
    const int l = t & 63;
    const int l31 = l & 31, lh = l >> 5;

    f32x16 acc = (f32x16)0.f;
#pragma unroll
    for (int kc = 0; kc < 8; ++kc) {
        half8 af = *(const half8*)(xa + l31 * LDA + kc * 16 + lh * 8);
        half8 bf = *(const half8*)(wb + (wid * 32 + l31) * LDA + kc * 16 + lh * 8);
        acc = __builtin_amdgcn_mfma_f32_32x32x16_f16(af, bf, acc, 0, 0, 0);
    }

    const int n = ng * 128 + wid * 32 + l31;
    float alpha = g1[n] * rsqrtf(v1[n] + EPS);
    if (which == 0) {
        float bias = alpha * b1[n] + be1[n] - m1[n] * alpha;
#pragma unroll
        for (int r = 0; r < 16; ++r) {
            int m = (r & 3) + 8 * (r >> 2) + 4 * lh;
            hxh[(size_t)(rowbase + m) * 512 + n] = (_Float16)(alpha * acc[r] + bias);
        }
    } else {
        // hy in fragment layout (per-b region of 65536 halves; K16=32)
        const int ks = n >> 4, lhh = (n >> 3) & 1, c = n & 7;
#pragma unroll
        for (int r = 0; r < 16; ++r) {
            int m = (r & 3) + 8 * (r >> 2) + 4 * lh;
            int R = rowbase + m;                // global row = b*128 + j
            int bb = R >> 7, j = R & 127;
            int addr = bb * 65536 + ((j >> 5) * 32 + ks) * 512 + lhh * 256 + (j & 31) * 8 + c;
            hyh[addr] = (_Float16)(alpha * acc[r]);
        }
    }
}

// ---------------------------------------------------------------------------
// fused: one block per (b, i-pair). 1024 threads = 16 waves, 1 block/CU.
// r12 structure + w2 ALSO staged in LDS: the consume loop is now pure
// ds_read -> MFMA (no latency-exposed global loads in the MFMA loop; all
// global staging loads are issued right after the previous barrier and
// consumed a full chunk later). a1 = relu(hx+hy) staged once (zero
// redundancy). K-chunk 64, both buffers double-buffered:
// a1 [2][32][512] 64 KB + w2t [2][32][512] 64 KB, aliasing tail regions.
// Bias via MFMA C-init. Tails: two concurrent 8-wave teams (r11, proven).
// ---------------------------------------------------------------------------
__global__ __launch_bounds__(1024, 4)
void fused_kernel(
    const _Float16* __restrict__ hxh, const _Float16* __restrict__ hyh,
    const _Float16* __restrict__ w2h, const _Float16* __restrict__ w3h,
    const _Float16* __restrict__ w4h,
    const float* __restrict__ b2f, const float* __restrict__ b3f,
    const float* __restrict__ b4,
    float* __restrict__ out)
{
    constexpr int LD2 = 264;   // a2 row stride (halves), 528 B (proven 0-conflict)
    constexpr int LD3 = 136;   // a3 row stride (halves), 272 B
    constexpr int LDE = 68;    // es row stride (f32), 272 B
    constexpr int REG = 67584; // per-team tail region bytes

    __shared__ char smem[8192 + 2 * REG] __attribute__((aligned(16)));
    _Float16* hxs = (_Float16*)smem;             // [2][512] f16  2048 B
    float* spart  = (float*)(smem + 2048);       // [2][8][64]    4096 B
    float* ss     = (float*)(smem + 6144);       // [2][64]        512 B
    char* R1 = smem + 8192;                      // team regions (tail phase)
    // L2 phase aliasing: a1 [2 bufs][32 slices][512] = 65536 B at R1,
    // w2t [2 bufs][32 slices][512] = 65536 B at R1+65536. Both dead before
    // the a2 epilogue writes (barrier-separated).
    _Float16* a1  = (_Float16*)R1;
    _Float16* w2t = (_Float16*)(R1 + 65536);

    const int b  = blockIdx.x >> 6;              // 0..7
    const int ip = blockIdx.x & 63;              // 0..63
    const int i0 = ip * 2;
    const int t = threadIdx.x;
    const int wid = t >> 6;                      // 0..15
    const int l   = t & 63;
    const int l31 = l & 31;
    const int lh  = l >> 5;

    if (t < 128) {
        int iv = t >> 6;                         // 0,1
        *(half8*)(hxs + iv * 512 + (t & 63) * 8) =
            *(const half8*)(hxh + (size_t)(b * 128 + i0 + iv) * 512 + (t & 63) * 8);
    }
    __syncthreads();

    // ---------------- layer 2: [128x512] @ [256x512]^T ----------------
    // a1 staging: wave -> (srg, sksl); handles both i for its slice
    const int srg = wid >> 2, sksl = wid & 3;
    const _Float16* hysrc = hyh + (size_t)b * 65536
                          + (size_t)(srg * 32 + sksl) * 512 + l * 8;
    // w2 staging: wave -> n-group sng (0..7), 2 consecutive kslices
    const int sng = wid >> 1, sk0 = (wid & 1) * 2;
    const _Float16* w2src = w2h + (size_t)(sng * 32 + sk0) * 512 + l * 8;
    // consume grid: 4M x 4N (wm = rowgroup, wn = 2 colgroups), tile x 2 i
    const int wm = wid >> 2, wn = wid & 3;

    const float bb0 = b2f[wn * 64 + l31];
    const float bb1 = b2f[wn * 64 + 32 + l31];
    f32x16 d0 = (f32x16)bb0, d1 = (f32x16)bb1;   // i0
    f32x16 e0 = (f32x16)bb0, e1 = (f32x16)bb1;   // i1

    half8 hyreg, rw0, rw1;                       // staged fragments (named)

    auto SLOAD = [&](int c) {                    // issue next chunk's gloads
        hyreg = *(const half8*)(hysrc + (size_t)c * 4 * 512);
        rw0   = *(const half8*)(w2src + (size_t)c * 4 * 512);
        rw1   = *(const half8*)(w2src + (size_t)(c * 4 + 1) * 512);
    };
    auto SFIN = [&](int c) {                     // relu both i + LDS writes
        const int ksg = c * 4 + sksl;
        half8 hx0 = *(const half8*)(hxs + ksg * 16 + lh * 8);
        half8 hx1 = *(const half8*)(hxs + 512 + ksg * 16 + lh * 8);
        half8 s0 = hyreg + hx0;
        half8 s1 = hyreg + hx1;
        half8 a0, a1f;
#pragma unroll
        for (int cc = 0; cc < 8; ++cc) {
            a0[cc]  = s0[cc] > (_Float16)0.f ? s0[cc] : (_Float16)0.f;
            a1f[cc] = s1[cc] > (_Float16)0.f ? s1[cc] : (_Float16)0.f;
        }
        _Float16* dst = a1 + (size_t)((c & 1) * 32 + srg * 4 + sksl) * 512 + l * 8;
        *(half8*)dst = a0;
        *(half8*)(dst + 16 * 512) = a1f;         // i1 slices at +16
        _Float16* wdst = w2t + (size_t)((c & 1) * 32 + sng * 4 + sk0) * 512 + l * 8;
        *(half8*)wdst = rw0;
        *(half8*)(wdst + 512) = rw1;
    };
    auto CONSUME = [&](int c) {
        const _Float16* ab0 = a1 + (size_t)((c & 1) * 32 + wm * 4) * 512 + l * 8;
        const _Float16* ab1 = ab0 + 16 * 512;
        const _Float16* wb0 = w2t + (size_t)((c & 1) * 32 + (2 * wn) * 4) * 512 + l * 8;
        const _Float16* wb1 = wb0 + 4 * 512;
#pragma unroll
        for (int ksl = 0; ksl < 4; ++ksl) {
            half8 Ai0 = *(const half8*)(ab0 + ksl * 512);
            half8 Ai1 = *(const half8*)(ab1 + ksl * 512);
            half8 Bx  = *(const half8*)(wb0 + ksl * 512);
            half8 By  = *(const half8*)(wb1 + ksl * 512);
            d0 = __builtin_amdgcn_mfma_f32_32x32x16_f16(Ai0, Bx, d0, 0, 0, 0);
            d1 = __builtin_amdgcn_mfma_f32_32x32x16_f16(Ai0, By, d1, 0, 0, 0);
            e0 = __builtin_amdgcn_mfma_f32_32x32x16_f16(Ai1, Bx, e0, 0, 0, 0);
            e1 = __builtin_amdgcn_mfma_f32_32x32x16_f16(Ai1, By, e1, 0, 0, 0);
        }
    };

    SLOAD(0);
    SFIN(0);
    __syncthreads();
#pragma unroll 2
    for (int c = 0; c < 8; ++c) {
        if (c < 7) SLOAD(c + 1);                 // gload latency hides under MFMA
        CONSUME(c);                              // pure ds_read -> MFMA
        if (c < 7) SFIN(c + 1);                  // writes buf (c+1)&1
        __syncthreads();                         // chunk ready / read done
    }

    // ---------------- L2 epilogue: all 16 waves fill BOTH team regions ------
    {
        _Float16* a2_0 = (_Float16*)R1;          // team0 = i0
        _Float16* a2_1 = (_Float16*)(R1 + REG);  // team1 = i1
#pragma unroll
        for (int r = 0; r < 16; ++r) {
            int m = wm * 32 + (r & 3) + 8 * (r >> 2) + 4 * lh;
            a2_0[m * LD2 + wn * 64 + l31]      = (_Float16)fmaxf(d0[r], 0.f);
            a2_0[m * LD2 + wn * 64 + 32 + l31] = (_Float16)fmaxf(d1[r], 0.f);
            a2_1[m * LD2 + wn * 64 + l31]      = (_Float16)fmaxf(e0[r], 0.f);
            a2_1[m * LD2 + wn * 64 + 32 + l31] = (_Float16)fmaxf(e1[r], 0.f);
        }
    }
    __syncthreads();

    // ---------------- concurrent team tails (team = wid>>3, one i each) -----
    const int team = wid >> 3;
    const int tw   = wid & 7;                    // team-local wave id
    char* reg = R1 + team * REG;
    _Float16* a2 = (_Float16*)reg;               // [128][264]
    _Float16* a3 = (_Float16*)reg;               // [128][136] (after L3)
    float*    es = (float*)reg;                  // [128][68]  (after L4)
    float* spart_t = spart + team * 512;
    float* ss_t    = ss + team * 64;
    const int iv = i0 + team;

    // layer 3: [128x256] @ [128x256]^T, 2M x 4N per team, B = global fragments
    const int wm3 = tw >> 2, wn3 = tw & 3;
    f32x16 g0, g1;
    {
        float b3v = b3f[wn3 * 32 + l31];
        g0 = (f32x16)b3v;
        g1 = (f32x16)b3v;
    }
#pragma unroll 4
    for (int kc = 0; kc < 16; ++kc) {
        half8 bfr = *(const half8*)(w3h + (wn3 * 16 + kc) * 512 + l * 8);
        half8 af0 = *(const half8*)(a2 + (wm3 * 64 + l31) * LD2 + kc * 16 + lh * 8);
        half8 af1 = *(const half8*)(a2 + (wm3 * 64 + 32 + l31) * LD2 + kc * 16 + lh * 8);
        g0 = __builtin_amdgcn_mfma_f32_32x32x16_f16(af0, bfr, g0, 0, 0, 0);
        g1 = __builtin_amdgcn_mfma_f32_32x32x16_f16(af1, bfr, g1, 0, 0, 0);
    }
    __syncthreads();
#pragma unroll
    for (int mt = 0; mt < 2; ++mt)
#pragma unroll
        for (int r = 0; r < 16; ++r) {
            int m = wm3 * 64 + mt * 32 + (r & 3) + 8 * (r >> 2) + 4 * lh;
            a3[m * LD3 + wn3 * 32 + l31] = (_Float16)fmaxf(mt ? g1[r] : g0[r], 0.f);
        }
    __syncthreads();

    // layer 4: [128x128] @ [64x128]^T, 4M x 2N per team
    const int wm4 = tw >> 1, wn4 = tw & 1;
    f32x16 acc4 = (f32x16)(b4[wn4 * 32 + l31]);
#pragma unroll
    for (int kc = 0; kc < 8; ++kc) {
        half8 afr = *(const half8*)(a3 + (wm4 * 32 + l31) * LD3 + kc * 16 + lh * 8);
        half8 bfr = *(const half8*)(w4h + (wn4 * 8 + kc) * 512 + l * 8);
        acc4 = __builtin_amdgcn_mfma_f32_32x32x16_f16(afr, bfr, acc4, 0, 0, 0);
    }
    __syncthreads();  // a3 reads done before es overwrites it
#pragma unroll
    for (int r = 0; r < 16; ++r) {
        int m = wm4 * 32 + (r & 3) + 8 * (r >> 2) + 4 * lh;
        es[m * LDE + wn4 * 32 + l31] = acc4[r];
    }
    __syncthreads();

    // s = sum_j e ; out[j] = sum_k e[j][k]*s[k]   (per team)
    {
        float sv = 0.f;
#pragma unroll
        for (int jj = 0; jj < 16; ++jj) sv += es[(tw + jj * 8) * LDE + l];
        spart_t[tw * 64 + l] = sv;
    }
    __syncthreads();
    if ((t & 511) < 64) {
        int tt = t & 63;
        float s2 = 0.f;
#pragma unroll
        for (int r = 0; r < 8; ++r) s2 += spart_t[r * 64 + tt];
        ss_t[tt] = s2;
    }
    __syncthreads();
    {
        const int tt = t & 511;
        const int j = tt >> 2, q = tt & 3;
        float p = 0.f;
#pragma unroll
        for (int c = 0; c < 16; ++c) {
            int k = q + 4 * c;               // k-interleaved: 2 lanes/bank
            p += es[j * LDE + k] * ss_t[k];
        }
        p += __shfl_xor(p, 1);
        p += __shfl_xor(p, 2);
        if (q == 0) out[(size_t)(b * 128 + iv) * 128 + j] = p;
    }
}

// ---------------------------------------------------------------------------
extern "C" void kernel_launch(void* const* d_in, const int* in_sizes, int n_in,
                              void* d_out, int out_size, void* d_ws, size_t ws_size,
                              hipStream_t stream)
{
    (void)in_sizes; (void)n_in; (void)out_size; (void)ws_size;

    const float* x   = (const float*)d_in[0];
    const float* y   = (const float*)d_in[1];
    const float* w1  = (const float*)d_in[2];
    const float* b1  = (const float*)d_in[3];
    const float* g1  = (const float*)d_in[4];
    const float* be1 = (const float*)d_in[5];
    const float* m1  = (const float*)d_in[6];
    const float* v1  = (const float*)d_in[7];
    const float* w2  = (const float*)d_in[8];
    const float* b2  = (const float*)d_in[9];
    const float* g2  = (const float*)d_in[10];
    const float* be2 = (const float*)d_in[11];
    const float* m2  = (const float*)d_in[12];
    const float* v2  = (const float*)d_in[13];
    const float* w3  = (const float*)d_in[14];
    const float* b3  = (const float*)d_in[15];
    const float* g3  = (const float*)d_in[16];
    const float* be3 = (const float*)d_in[17];
    const float* m3  = (const float*)d_in[18];
    const float* v3  = (const float*)d_in[19];
    const float* w4  = (const float*)d_in[20];
    const float* b4  = (const float*)d_in[21];
    float* out = (float*)d_out;

    // workspace layout (~2.44 MB)
    float* b2f = (float*)d_ws;                 // 256 f32
    float* b3f = b2f + 256;                    // 128 f32
    _Float16* w2h = (_Float16*)(b3f + 128);    // 131072 f16 (fragment layout)
    _Float16* w3h = w2h + 131072;              // 32768 f16  (fragment layout)
    _Float16* w4h = w3h + 32768;               // 8192 f16   (fragment layout)
    _Float16* hxh = w4h + 8192;                // 524288 f16 (linear)
    _Float16* hyh = hxh + 524288;              // 524288 f16 (fragment layout per b)

    hipLaunchKernelGGL(pre_kernel, dim3(320), dim3(256), 0, stream,
                       x, y, w1, b1, g1, be1, m1, v1,
                       w2, b2, g2, be2, m2, v2,
                       w3, b3, g3, be3, m3, v3,
                       w4,
                       hxh, hyh, w2h, w3h, w4h, b2f, b3f);

    hipLaunchKernelGGL(fused_kernel, dim3(512), dim3(1024), 0, stream,
                       hxh, hyh, w2h, w3h, w4h, b2f, b3f, b4, out);
}

// Round 17
// 61.654 us; speedup vs baseline: 1.1131x; 1.0117x over previous
//
#include <hip/hip_runtime.h>

#define EPS 1e-5f

typedef _Float16 half8 __attribute__((ext_vector_type(8)));
typedef _Float16 half4 __attribute__((ext_vector_type(4)));
typedef float f32x16 __attribute__((ext_vector_type(16)));
typedef float f32x4v __attribute__((ext_vector_type(4)));

// Fragment layout for an [R x K] f16 matrix consumed as 32-row MFMA operand:
// element (row, k) -> ((row>>5)*(K/16) + (k>>4))*512 + ((k>>3)&1)*256 + (row&31)*8 + (k&7)
// wave fragment load for (rowgroup rg, kslice ks) = base + (rg*(K/16)+ks)*512 + lane*8
// = 64 lanes x 16 B contiguous (perfectly coalesced).

// ---------------------------------------------------------------------------
// pre_kernel: blocks 0..255 = hxhy via MFMA (w1 consumed directly, alpha/bias
// folded in epilogue; hy written in fragment layout); blocks 256..319 =
// weight prep (BN-fold w2/w3, cast w4; all written in fragment layout).
// ---------------------------------------------------------------------------
__global__ __launch_bounds__(256)
void pre_kernel(
    const float* __restrict__ x, const float* __restrict__ y,
    const float* __restrict__ w1, const float* __restrict__ b1,
    const float* __restrict__ g1, const float* __restrict__ be1,
    const float* __restrict__ m1, const float* __restrict__ v1,
    const float* __restrict__ w2, const float* __restrict__ b2,
    const float* __restrict__ g2, const float* __restrict__ be2,
    const float* __restrict__ m2, const float* __restrict__ v2,
    const float* __restrict__ w3, const float* __restrict__ b3,
    const float* __restrict__ g3, const float* __restrict__ be3,
    const float* __restrict__ m3, const float* __restrict__ v3,
    const float* __restrict__ w4,
    _Float16* __restrict__ hxh, _Float16* __restrict__ hyh,
    _Float16* __restrict__ w2h, _Float16* __restrict__ w3h,
    _Float16* __restrict__ w4h,
    float* __restrict__ b2f, float* __restrict__ b3f)
{
    const int t = threadIdx.x;

    if (blockIdx.x >= 256) {
        // ---------------- prep part (fragment-scattered writes) ----------------
        int tid = (blockIdx.x - 256) * 256 + t;
        const int nth = 64 * 256;
        for (int idx = tid; idx < 256 * 512; idx += nth) {
            int n = idx >> 9, k = idx & 511;
            float a = g2[n] * rsqrtf(v2[n] + EPS);
            int addr = ((n >> 5) * 32 + (k >> 4)) * 512 + ((k >> 3) & 1) * 256 + (n & 31) * 8 + (k & 7);
            w2h[addr] = (_Float16)(a * w2[idx]);
        }
        for (int idx = tid; idx < 128 * 256; idx += nth) {
            int n = idx >> 8, k = idx & 255;
            float a = g3[n] * rsqrtf(v3[n] + EPS);
            int addr = ((n >> 5) * 16 + (k >> 4)) * 512 + ((k >> 3) & 1) * 256 + (n & 31) * 8 + (k & 7);
            w3h[addr] = (_Float16)(a * w3[idx]);
        }
        for (int idx = tid; idx < 64 * 128; idx += nth) {
            int n = idx >> 7, k = idx & 127;
            int addr = ((n >> 5) * 8 + (k >> 4)) * 512 + ((k >> 3) & 1) * 256 + (n & 31) * 8 + (k & 7);
            w4h[addr] = (_Float16)w4[idx];
        }
        if (tid < 256) {
            float a = g2[tid] * rsqrtf(v2[tid] + EPS);
            b2f[tid] = a * b2[tid] + be2[tid] - m2[tid] * a;
        } else if (tid < 384) {
            int n = tid - 256;
            float a = g3[n] * rsqrtf(v3[n] + EPS);
            b3f[n] = a * b3[n] + be3[n] - m3[n] * a;
        }
        return;
    }

    // ---------------- hxhy part ----------------
    // bid: rg = 32-row group (32), ng = 128-col group (4), which = x/y (2)
    const int rg = blockIdx.x & 31;
    const int ng = (blockIdx.x >> 5) & 3;
    const int which = blockIdx.x >> 7;

    constexpr int LDA = 136;  // 272 B row stride
    __shared__ _Float16 sh[32 * 136 + 128 * 136] __attribute__((aligned(16)));
    _Float16* xa = sh;                 // [32][136]
    _Float16* wb = sh + 32 * 136;      // [128][136]

    const int rowbase = rg * 32;
    const float* src = which ? y : x;

    // stage A: 32 rows x 128 f32 -> f16
#pragma unroll
    for (int p = 0; p < 4; ++p) {
        int c = p * 256 + t;               // 0..1023 float4-chunks
        int r = c >> 5, fo = (c & 31) * 4;
        f32x4v v = *(const f32x4v*)(src + (size_t)(rowbase + r) * 128 + fo);
        half4 h; h[0] = (_Float16)v[0]; h[1] = (_Float16)v[1];
        h[2] = (_Float16)v[2]; h[3] = (_Float16)v[3];
        *(half4*)(xa + r * LDA + fo) = h;
    }
    // stage B: 128 n-rows x 128 k f32 -> f16 (w1 row-major, k-offset by which)
#pragma unroll
    for (int p = 0; p < 16; ++p) {
        int c = p * 256 + t;               // 0..4095
        int n = c >> 5, fo = (c & 31) * 4;
        f32x4v v = *(const f32x4v*)(w1 + (size_t)(ng * 128 + n) * 256 + which * 128 + fo);
        half4 h; h[0] = (_Float16)v[0]; h[1] = (_Float16)v[1];
        h[2] = (_Float16)v[2]; h[3] = (_Float16)v[3];
        *(half4*)(wb + n * LDA + fo) = h;
    }
    __syncthreads();

    const int wid = t >> 6;
    const int l = t & 63;
    const int l31 = l & 31, lh = l >> 5;

    f32x16 acc = (f32x16)0.f;
#pragma unroll
    for (int kc = 0; kc < 8; ++kc) {
        half8 af = *(const half8*)(xa + l31 * LDA + kc * 16 + lh * 8);
        half8 bf = *(const half8*)(wb + (wid * 32 + l31) * LDA + kc * 16 + lh * 8);
        acc = __builtin_amdgcn_mfma_f32_32x32x16_f16(af, bf, acc, 0, 0, 0);
    }

    const int n = ng * 128 + wid * 32 + l31;
    float alpha = g1[n] * rsqrtf(v1[n] + EPS);
    if (which == 0) {
        float bias = alpha * b1[n] + be1[n] - m1[n] * alpha;
#pragma unroll
        for (int r = 0; r < 16; ++r) {
            int m = (r & 3) + 8 * (r >> 2) + 4 * lh;
            hxh[(size_t)(rowbase + m) * 512 + n] = (_Float16)(alpha * acc[r] + bias);
        }
    } else {
        // hy in fragment layout (per-b region of 65536 halves; K16=32)
        const int ks = n >> 4, lhh = (n >> 3) & 1, c = n & 7;
#pragma unroll
        for (int r = 0; r < 16; ++r) {
            int m = (r & 3) + 8 * (r >> 2) + 4 * lh;
            int R = rowbase + m;                // global row = b*128 + j
            int bb = R >> 7, j = R & 127;
            int addr = bb * 65536 + ((j >> 5) * 32 + ks) * 512 + lhh * 256 + (j & 31) * 8 + c;
            hyh[addr] = (_Float16)(alpha * acc[r]);
        }
    }
}

// ---------------------------------------------------------------------------
// fused: one block per (b, i-pair). 1024 threads = 16 waves, 1 block/CU.
// r16 structure (best: 58.5 us fused): a1+w2 both LDS-staged, pure
// ds_read->MFMA consume, K-chunk 64 double-buffered, bias via MFMA C-init,
// two concurrent 8-wave team tails. THIS ROUND: +s_setprio(1) around the
// MFMA clusters (T5) -- within a chunk waves are at different roles
// (SLOAD/CONSUME/SFIN, no intra-chunk barrier), so the CU scheduler can
// prefer MFMA-issuing waves for shared issue/LDS ports.
// ---------------------------------------------------------------------------
__global__ __launch_bounds__(1024, 4)
void fused_kernel(
    const _Float16* __restrict__ hxh, const _Float16* __restrict__ hyh,
    const _Float16* __restrict__ w2h, const _Float16* __restrict__ w3h,
    const _Float16* __restrict__ w4h,
    const float* __restrict__ b2f, const float* __restrict__ b3f,
    const float* __restrict__ b4,
    float* __restrict__ out)
{
    constexpr int LD2 = 264;   // a2 row stride (halves), 528 B (proven 0-conflict)
    constexpr int LD3 = 136;   // a3 row stride (halves), 272 B
    constexpr int LDE = 68;    // es row stride (f32), 272 B
    constexpr int REG = 67584; // per-team tail region bytes

    __shared__ char smem[8192 + 2 * REG] __attribute__((aligned(16)));
    _Float16* hxs = (_Float16*)smem;             // [2][512] f16  2048 B
    float* spart  = (float*)(smem + 2048);       // [2][8][64]    4096 B
    float* ss     = (float*)(smem + 6144);       // [2][64]        512 B
    char* R1 = smem + 8192;                      // team regions (tail phase)
    // L2 phase aliasing: a1 [2 bufs][32 slices][512] = 65536 B at R1,
    // w2t [2 bufs][32 slices][512] = 65536 B at R1+65536. Both dead before
    // the a2 epilogue writes (barrier-separated).
    _Float16* a1  = (_Float16*)R1;
    _Float16* w2t = (_Float16*)(R1 + 65536);

    const int b  = blockIdx.x >> 6;              // 0..7
    const int ip = blockIdx.x & 63;              // 0..63
    const int i0 = ip * 2;
    const int t = threadIdx.x;
    const int wid = t >> 6;                      // 0..15
    const int l   = t & 63;
    const int l31 = l & 31;
    const int lh  = l >> 5;

    if (t < 128) {
        int iv = t >> 6;                         // 0,1
        *(half8*)(hxs + iv * 512 + (t & 63) * 8) =
            *(const half8*)(hxh + (size_t)(b * 128 + i0 + iv) * 512 + (t & 63) * 8);
    }
    __syncthreads();

    // ---------------- layer 2: [128x512] @ [256x512]^T ----------------
    // a1 staging: wave -> (srg, sksl); handles both i for its slice
    const int srg = wid >> 2, sksl = wid & 3;
    const _Float16* hysrc = hyh + (size_t)b * 65536
                          + (size_t)(srg * 32 + sksl) * 512 + l * 8;
    // w2 staging: wave -> n-group sng (0..7), 2 consecutive kslices
    const int sng = wid >> 1, sk0 = (wid & 1) * 2;
    const _Float16* w2src = w2h + (size_t)(sng * 32 + sk0) * 512 + l * 8;
    // consume grid: 4M x 4N (wm = rowgroup, wn = 2 colgroups), tile x 2 i
    const int wm = wid >> 2, wn = wid & 3;

    const float bb0 = b2f[wn * 64 + l31];
    const float bb1 = b2f[wn * 64 + 32 + l31];
    f32x16 d0 = (f32x16)bb0, d1 = (f32x16)bb1;   // i0
    f32x16 e0 = (f32x16)bb0, e1 = (f32x16)bb1;   // i1

    half8 hyreg, rw0, rw1;                       // staged fragments (named)

    auto SLOAD = [&](int c) {                    // issue next chunk's gloads
        hyreg = *(const half8*)(hysrc + (size_t)c * 4 * 512);
        rw0   = *(const half8*)(w2src + (size_t)c * 4 * 512);
        rw1   = *(const half8*)(w2src + (size_t)(c * 4 + 1) * 512);
    };
    auto SFIN = [&](int c) {                     // relu both i + LDS writes
        const int ksg = c * 4 + sksl;
        half8 hx0 = *(const half8*)(hxs + ksg * 16 + lh * 8);
        half8 hx1 = *(const half8*)(hxs + 512 + ksg * 16 + lh * 8);
        half8 s0 = hyreg + hx0;
        half8 s1 = hyreg + hx1;
        half8 a0, a1f;
#pragma unroll
        for (int cc = 0; cc < 8; ++cc) {
            a0[cc]  = s0[cc] > (_Float16)0.f ? s0[cc] : (_Float16)0.f;
            a1f[cc] = s1[cc] > (_Float16)0.f ? s1[cc] : (_Float16)0.f;
        }
        _Float16* dst = a1 + (size_t)((c & 1) * 32 + srg * 4 + sksl) * 512 + l * 8;
        *(half8*)dst = a0;
        *(half8*)(dst + 16 * 512) = a1f;         // i1 slices at +16
        _Float16* wdst = w2t + (size_t)((c & 1) * 32 + sng * 4 + sk0) * 512 + l * 8;
        *(half8*)wdst = rw0;
        *(half8*)(wdst + 512) = rw1;
    };
    auto CONSUME = [&](int c) {
        const _Float16* ab0 = a1 + (size_t)((c & 1) * 32 + wm * 4) * 512 + l * 8;
        const _Float16* ab1 = ab0 + 16 * 512;
        const _Float16* wb0 = w2t + (size_t)((c & 1) * 32 + (2 * wn) * 4) * 512 + l * 8;
        const _Float16* wb1 = wb0 + 4 * 512;
        __builtin_amdgcn_s_setprio(1);           // T5: prefer MFMA-issuing waves
#pragma unroll
        for (int ksl = 0; ksl < 4; ++ksl) {
            half8 Ai0 = *(const half8*)(ab0 + ksl * 512);
            half8 Ai1 = *(const half8*)(ab1 + ksl * 512);
            half8 Bx  = *(const half8*)(wb0 + ksl * 512);
            half8 By  = *(const half8*)(wb1 + ksl * 512);
            d0 = __builtin_amdgcn_mfma_f32_32x32x16_f16(Ai0, Bx, d0, 0, 0, 0);
            d1 = __builtin_amdgcn_mfma_f32_32x32x16_f16(Ai0, By, d1, 0, 0, 0);
            e0 = __builtin_amdgcn_mfma_f32_32x32x16_f16(Ai1, Bx, e0, 0, 0, 0);
            e1 = __builtin_amdgcn_mfma_f32_32x32x16_f16(Ai1, By, e1, 0, 0, 0);
        }
        __builtin_amdgcn_s_setprio(0);
    };

    SLOAD(0);
    SFIN(0);
    __syncthreads();
#pragma unroll 2
    for (int c = 0; c < 8; ++c) {
        if (c < 7) SLOAD(c + 1);                 // gload latency hides under MFMA
        CONSUME(c);                              // pure ds_read -> MFMA
        if (c < 7) SFIN(c + 1);                  // writes buf (c+1)&1
        __syncthreads();                         // chunk ready / read done
    }

    // ---------------- L2 epilogue: all 16 waves fill BOTH team regions ------
    {
        _Float16* a2_0 = (_Float16*)R1;          // team0 = i0
        _Float16* a2_1 = (_Float16*)(R1 + REG);  // team1 = i1
#pragma unroll
        for (int r = 0; r < 16; ++r) {
            int m = wm * 32 + (r & 3) + 8 * (r >> 2) + 4 * lh;
            a2_0[m * LD2 + wn * 64 + l31]      = (_Float16)fmaxf(d0[r], 0.f);
            a2_0[m * LD2 + wn * 64 + 32 + l31] = (_Float16)fmaxf(d1[r], 0.f);
            a2_1[m * LD2 + wn * 64 + l31]      = (_Float16)fmaxf(e0[r], 0.f);
            a2_1[m * LD2 + wn * 64 + 32 + l31] = (_Float16)fmaxf(e1[r], 0.f);
        }
    }
    __syncthreads();

    // ---------------- concurrent team tails (team = wid>>3, one i each) -----
    const int team = wid >> 3;
    const int tw   = wid & 7;                    // team-local wave id
    char* reg = R1 + team * REG;
    _Float16* a2 = (_Float16*)reg;               // [128][264]
    _Float16* a3 = (_Float16*)reg;               // [128][136] (after L3)
    float*    es = (float*)reg;                  // [128][68]  (after L4)
    float* spart_t = spart + team * 512;
    float* ss_t    = ss + team * 64;
    const int iv = i0 + team;

    // layer 3: [128x256] @ [128x256]^T, 2M x 4N per team, B = global fragments
    const int wm3 = tw >> 2, wn3 = tw & 3;
    f32x16 g0, g1;
    {
        float b3v = b3f[wn3 * 32 + l31];
        g0 = (f32x16)b3v;
        g1 = (f32x16)b3v;
    }
    __builtin_amdgcn_s_setprio(1);
#pragma unroll 4
    for (int kc = 0; kc < 16; ++kc) {
        half8 bfr = *(const half8*)(w3h + (wn3 * 16 + kc) * 512 + l * 8);
        half8 af0 = *(const half8*)(a2 + (wm3 * 64 + l31) * LD2 + kc * 16 + lh * 8);
        half8 af1 = *(const half8*)(a2 + (wm3 * 64 + 32 + l31) * LD2 + kc * 16 + lh * 8);
        g0 = __builtin_amdgcn_mfma_f32_32x32x16_f16(af0, bfr, g0, 0, 0, 0);
        g1 = __builtin_amdgcn_mfma_f32_32x32x16_f16(af1, bfr, g1, 0, 0, 0);
    }
    __builtin_amdgcn_s_setprio(0);
    __syncthreads();
#pragma unroll
    for (int mt = 0; mt < 2; ++mt)
#pragma unroll
        for (int r = 0; r < 16; ++r) {
            int m = wm3 * 64 + mt * 32 + (r & 3) + 8 * (r >> 2) + 4 * lh;
            a3[m * LD3 + wn3 * 32 + l31] = (_Float16)fmaxf(mt ? g1[r] : g0[r], 0.f);
        }
    __syncthreads();

    // layer 4: [128x128] @ [64x128]^T, 4M x 2N per team
    const int wm4 = tw >> 1, wn4 = tw & 1;
    f32x16 acc4 = (f32x16)(b4[wn4 * 32 + l31]);
    __builtin_amdgcn_s_setprio(1);
#pragma unroll
    for (int kc = 0; kc < 8; ++kc) {
        half8 afr = *(const half8*)(a3 + (wm4 * 32 + l31) * LD3 + kc * 16 + lh * 8);
        half8 bfr = *(const half8*)(w4h + (wn4 * 8 + kc) * 512 + l * 8);
        acc4 = __builtin_amdgcn_mfma_f32_32x32x16_f16(afr, bfr, acc4, 0, 0, 0);
    }
    __builtin_amdgcn_s_setprio(0);
    __syncthreads();  // a3 reads done before es overwrites it
#pragma unroll
    for (int r = 0; r < 16; ++r) {
        int m = wm4 * 32 + (r & 3) + 8 * (r >> 2) + 4 * lh;
        es[m * LDE + wn4 * 32 + l31] = acc4[r];
    }
    __syncthreads();

    // s = sum_j e ; out[j] = sum_k e[j][k]*s[k]   (per team)
    {
        float sv = 0.f;
#pragma unroll
        for (int jj = 0; jj < 16; ++jj) sv += es[(tw + jj * 8) * LDE + l];
        spart_t[tw * 64 + l] = sv;
    }
    __syncthreads();
    if ((t & 511) < 64) {
        int tt = t & 63;
        float s2 = 0.f;
#pragma unroll
        for (int r = 0; r < 8; ++r) s2 += spart_t[r * 64 + tt];
        ss_t[tt] = s2;
    }
    __syncthreads();
    {
        const int tt = t & 511;
        const int j = tt >> 2, q = tt & 3;
        float p = 0.f;
#pragma unroll
        for (int c = 0; c < 16; ++c) {
            int k = q + 4 * c;               // k-interleaved: 2 lanes/bank
            p += es[j * LDE + k] * ss_t[k];
        }
        p += __shfl_xor(p, 1);
        p += __shfl_xor(p, 2);
        if (q == 0) out[(size_t)(b * 128 + iv) * 128 + j] = p;
    }
}

// ---------------------------------------------------------------------------
extern "C" void kernel_launch(void* const* d_in, const int* in_sizes, int n_in,
                              void* d_out, int out_size, void* d_ws, size_t ws_size,
                              hipStream_t stream)
{
    (void)in_sizes; (void)n_in; (void)out_size; (void)ws_size;

    const float* x   = (const float*)d_in[0];
    const float* y   = (const float*)d_in[1];
    const float* w1  = (const float*)d_in[2];
    const float* b1  = (const float*)d_in[3];
    const float* g1  = (const float*)d_in[4];
    const float* be1 = (const float*)d_in[5];
    const float* m1  = (const float*)d_in[6];
    const float* v1  = (const float*)d_in[7];
    const float* w2  = (const float*)d_in[8];
    const float* b2  = (const float*)d_in[9];
    const float* g2  = (const float*)d_in[10];
    const float* be2 = (const float*)d_in[11];
    const float* m2  = (const float*)d_in[12];
    const float* v2  = (const float*)d_in[13];
    const float* w3  = (const float*)d_in[14];
    const float* b3  = (const float*)d_in[15];
    const float* g3  = (const float*)d_in[16];
    const float* be3 = (const float*)d_in[17];
    const float* m3  = (const float*)d_in[18];
    const float* v3  = (const float*)d_in[19];
    const float* w4  = (const float*)d_in[20];
    const float* b4  = (const float*)d_in[21];
    float* out = (float*)d_out;

    // workspace layout (~2.44 MB)
    float* b2f = (float*)d_ws;                 // 256 f32
    float* b3f = b2f + 256;                    // 128 f32
    _Float16* w2h = (_Float16*)(b3f + 128);    // 131072 f16 (fragment layout)
    _Float16* w3h = w2h + 131072;              // 32768 f16  (fragment layout)
    _Float16* w4h = w3h + 32768;               // 8192 f16   (fragment layout)
    _Float16* hxh = w4h + 8192;                // 524288 f16 (linear)
    _Float16* hyh = hxh + 524288;              // 524288 f16 (fragment layout per b)

    hipLaunchKernelGGL(pre_kernel, dim3(320), dim3(256), 0, stream,
                       x, y, w1, b1, g1, be1, m1, v1,
                       w2, b2, g2, be2, m2, v2,
                       w3, b3, g3, be3, m3, v3,
                       w4,
                       hxh, hyh, w2h, w3h, w4h, b2f, b3f);

    hipLaunchKernelGGL(fused_kernel, dim3(512), dim3(1024), 0, stream,
                       hxh, hyh, w2h, w3h, w4h, b2f, b3f, b4, out);
}